// Round 11
// baseline (1674.739 us; speedup 1.0000x reference)
//
#include <hip/hip_runtime.h>
#include <hip/hip_bf16.h>

// Round 11: dynamic fusion. One worker kernel; each block does a 64-row qkv
// slab (round-10 structure); the 4th finisher of each batch (device-scope
// atomic counter in d_ws, zeroed by hipMemsetAsync each launch) runs the
// whole-batch attention inline, reading the just-written frag buffers
// (same-XCD L2 via swizzle). No spinning -> no deadlock; output bytes are
// identical regardless of which block executes attention.

typedef __attribute__((ext_vector_type(8))) short bf16x8;
typedef __attribute__((ext_vector_type(4))) float f32x4;

#define B_ 1024
#define T_ 256
#define C_ 384
#define H_ 64

static __device__ __forceinline__ unsigned short f2bf(float f) {
  unsigned int u = __float_as_uint(f);
  return (unsigned short)((u + 0x7fffu + ((u >> 16) & 1u)) >> 16);
}

static __device__ __forceinline__ float bf2f(unsigned short h) {
  return __uint_as_float(((unsigned int)h) << 16);
}

static __device__ __forceinline__ bf16x8 cvt8(float4 a, float4 b) {
  union { __hip_bfloat162 h[4]; bf16x8 v; } u;
  u.h[0] = __float22bfloat162_rn(make_float2(a.x, a.y));
  u.h[1] = __float22bfloat162_rn(make_float2(a.z, a.w));
  u.h[2] = __float22bfloat162_rn(make_float2(b.x, b.y));
  u.h[3] = __float22bfloat162_rn(make_float2(b.z, b.w));
  return u.v;
}

__global__ void pack_w_frag(const float* __restrict__ Wq, const float* __restrict__ Wk,
                            const float* __restrict__ Wv, unsigned short* __restrict__ wtp) {
  int id = blockIdx.x * 256 + threadIdx.x;
  if (id >= 144 * 512) return;
  int i = id & 7, lane = (id >> 3) & 63, f = id >> 9;
  int nt = f % 12, ks = f / 12;
  int n = nt * 16 + (lane & 15);
  int k = ks * 32 + (lane >> 4) * 8 + i;
  const float* W = (n < 64) ? Wq : ((n < 128) ? Wk : Wv);
  wtp[id] = f2bf(W[k * 64 + (n & 63)]);
}

__launch_bounds__(512, 4)
__global__ void head_worker(const float* __restrict__ x, const float* __restrict__ cosp,
                            const float* __restrict__ sinp,
                            const unsigned short* __restrict__ wtp,
                            unsigned short* __restrict__ qp,
                            unsigned short* __restrict__ kp,
                            unsigned short* __restrict__ vp,
                            unsigned int* __restrict__ cnt,
                            float* __restrict__ out) {
  // Union region: phase-1 x slab (48 KB, staging tiles aliased inside) and
  // attention-phase P buffers (8 waves x 16 x 264 shorts = 66 KB).
  __shared__ __align__(16) unsigned short shmem[8 * 16 * 264];
  __shared__ int doAttn;

  unsigned short* xs  = shmem;              // [64][384] swizzled bf16 slab
  unsigned short* Qst = xs;                 // [64][72]   (aliased, post-kloop)
  unsigned short* Kst = xs + 64 * 72;
  unsigned short* Vst = xs + 2 * 64 * 72;

  const int tid = threadIdx.x;
  const int w = tid >> 6;        // wave 0..7
  const int lane = tid & 63;
  const int l15 = lane & 15;
  const int lq = lane >> 4;

  // XCD-grouping swizzle: all 4 slab-blocks of a batch share bid%8 (same XCD
  // under round-robin placement; correctness does not depend on it).
  const int bid = blockIdx.x;            // 0..4095
  const int x8 = bid & 7, m = bid >> 3;
  const int b = (m >> 2) * 8 + x8;       // batch 0..1023
  const int g64 = m & 3;                 // slab within batch
  const int row0 = g64 * 64;

  const float* xb = x + (size_t)b * T_ * C_ + (size_t)row0 * C_;

  // ---- stage x slab with depth-2 chunk prefetch
  {
    float4 c0[2], c1[2];
    {
      const float* p = xb + (size_t)tid * 8;
      c0[0] = *(const float4*)p;
      c0[1] = *(const float4*)(p + 4);
    }
    #pragma unroll
    for (int s = 0; s < 6; ++s) {
      if (s + 1 < 6) {
        const float* p = xb + (size_t)((s + 1) * 512 + tid) * 8;
        c1[0] = *(const float4*)p;
        c1[1] = *(const float4*)(p + 4);
      }
      int c = s * 512 + tid;
      int row = c / 48;
      int cb = (c - row * 48) * 16;
      bf16x8 v = cvt8(c0[0], c0[1]);
      *(bf16x8*)((char*)xs + row * 768 + (cb ^ ((row & 7) << 4))) = v;
      c0[0] = c1[0]; c0[1] = c1[1];
    }
  }
  __syncthreads();

  // ---- K-loop: wave = (rset = w>>2) x (ng = w&3)
  const int ng = w & 3, rset = w >> 2;

  f32x4 acc[2][3];
  #pragma unroll
  for (int i = 0; i < 2; ++i)
    #pragma unroll
    for (int mm = 0; mm < 3; ++mm) {
      f32x4 z = {0.f, 0.f, 0.f, 0.f};
      acc[i][mm] = z;
    }

  const int arow0 = (rset * 2) * 16 + l15;
  const int arow1 = (rset * 2 + 1) * 16 + l15;
  const char* xrow0 = (const char*)xs + arow0 * 768;
  const char* xrow1 = (const char*)xs + arow1 * 768;
  const int asw0 = (arow0 & 7) << 4;
  const int asw1 = (arow1 & 7) << 4;

  #pragma unroll
  for (int ks = 0; ks < 12; ++ks) {
    bf16x8 bv[3];
    #pragma unroll
    for (int mm = 0; mm < 3; ++mm)
      bv[mm] = *(const bf16x8*)(wtp + ((size_t)(ks * 12 + ng * 3 + mm) * 64 + lane) * 8);
    bf16x8 a0 = *(const bf16x8*)(xrow0 + ((ks * 64 + lq * 16) ^ asw0));
    bf16x8 a1 = *(const bf16x8*)(xrow1 + ((ks * 64 + lq * 16) ^ asw1));
    #pragma unroll
    for (int mm = 0; mm < 3; ++mm) {
      acc[0][mm] = __builtin_amdgcn_mfma_f32_16x16x32_bf16(a0, bv[mm], acc[0][mm], 0, 0, 0);
      acc[1][mm] = __builtin_amdgcn_mfma_f32_16x16x32_bf16(a1, bv[mm], acc[1][mm], 0, 0, 0);
    }
  }
  __syncthreads();   // done reading xs before aliased staging tiles overwrite

  // ---- scatter-stage accumulators (pre-RoPE)
  #pragma unroll
  for (int i = 0; i < 2; ++i) {
    #pragma unroll
    for (int mm = 0; mm < 3; ++mm) {
      const int nt = ng * 3 + mm;
      #pragma unroll
      for (int j = 0; j < 4; ++j) {
        const int r64 = (rset * 2 + i) * 16 + lq * 4 + j;
        unsigned short v = f2bf(acc[i][mm][j]);
        if (nt < 4)      Qst[r64 * 72 + nt * 16 + l15] = v;
        else if (nt < 8) Kst[r64 * 72 + (nt - 4) * 16 + l15] = v;
        else             Vst[((nt - 8) * 16 + l15) * 72 + r64] = v;
      }
    }
  }
  __syncthreads();

  // ---- frag-line writeout: 24 x 1KB lines; RoPE fused on Q/K
  #pragma unroll
  for (int pass = 0; pass < 3; ++pass) {
    const int id = pass * 8 + w;
    if (id < 16) {
      const unsigned short* S = (id < 8) ? Qst : Kst;
      unsigned short* dst = (id < 8) ? qp : kp;
      const int lid = id & 7;
      const int tl = lid >> 1;
      const int ks2 = lid & 1;
      const int r64 = tl * 16 + l15;
      const int c0 = ks2 * 32 + lq * 8;
      const unsigned short* rowp = S + r64 * 72;
      bf16x8 mv = *(const bf16x8*)(rowp + c0);
      bf16x8 pv = *(const bf16x8*)(rowp + (c0 ^ 32));
      const int tglob = row0 + r64;
      const float* cp = cosp + tglob * H_ + c0;
      const float* sp = sinp + tglob * H_ + c0;
      float4 ca = *(const float4*)cp, cb = *(const float4*)(cp + 4);
      float4 sa = *(const float4*)sp, sb = *(const float4*)(sp + 4);
      const float sgn = ks2 ? 1.0f : -1.0f;
      bf16x8 ov;
      ov[0] = (short)f2bf(bf2f((unsigned short)mv[0]) * ca.x + sgn * bf2f((unsigned short)pv[0]) * sa.x);
      ov[1] = (short)f2bf(bf2f((unsigned short)mv[1]) * ca.y + sgn * bf2f((unsigned short)pv[1]) * sa.y);
      ov[2] = (short)f2bf(bf2f((unsigned short)mv[2]) * ca.z + sgn * bf2f((unsigned short)pv[2]) * sa.z);
      ov[3] = (short)f2bf(bf2f((unsigned short)mv[3]) * ca.w + sgn * bf2f((unsigned short)pv[3]) * sa.w);
      ov[4] = (short)f2bf(bf2f((unsigned short)mv[4]) * cb.x + sgn * bf2f((unsigned short)pv[4]) * sb.x);
      ov[5] = (short)f2bf(bf2f((unsigned short)mv[5]) * cb.y + sgn * bf2f((unsigned short)pv[5]) * sb.y);
      ov[6] = (short)f2bf(bf2f((unsigned short)mv[6]) * cb.z + sgn * bf2f((unsigned short)pv[6]) * sb.z);
      ov[7] = (short)f2bf(bf2f((unsigned short)mv[7]) * cb.w + sgn * bf2f((unsigned short)pv[7]) * sb.w);
      const int tile_glob = g64 * 4 + tl;
      *(bf16x8*)(dst + ((((size_t)b * 16 + tile_glob) * 2 + ks2) * 64 + lane) * 8) = ov;
    } else if (id < 24) {
      const int lid = id - 16;
      const int ntv = lid >> 1;
      const int kgl = lid & 1;
      const int ksg = g64 * 2 + kgl;
      bf16x8 fr = *(const bf16x8*)(Vst + (ntv * 16 + l15) * 72 + kgl * 32 + lq * 8);
      *(bf16x8*)(vp + ((((size_t)b * 4 + ntv) * 8 + ksg) * 64 + lane) * 8) = fr;
    }
  }

  // ---- publish + elect attention executor (4th finisher of this batch)
  __threadfence();       // per-thread release of the frag stores (device scope)
  __syncthreads();
  if (tid == 0) {
    unsigned int old = atomicAdd(&cnt[b], 1u);
    doAttn = (old == 3u);
  }
  __syncthreads();
  if (!doAttn) return;
  __threadfence();       // acquire side: invalidate stale cached lines

  // ================= attention for batch b (8 waves x tiles {w, 15-w}) ======
  unsigned short* Plds = shmem;               // reuse union region
  unsigned short* Pw = Plds + w * 16 * 264;
  float* ob = out + (size_t)b * T_ * H_;
  const int rt2[2] = {w, 15 - w};

  #pragma unroll
  for (int i = 0; i < 2; ++i) {
    const int ti = rt2[i];
    const int t0 = ti * 16;

    bf16x8 aq[2];
    #pragma unroll
    for (int ks2 = 0; ks2 < 2; ++ks2)
      aq[ks2] = *(const bf16x8*)(qp + ((((size_t)b * 16 + ti) * 2 + ks2) * 64 + lane) * 8);

    f32x4 sacc[16];
    #pragma unroll
    for (int si = 0; si < 16; ++si) {
      f32x4 z = {0.f, 0.f, 0.f, 0.f};
      sacc[si] = z;
    }

    #pragma unroll
    for (int si = 0; si < 16; ++si) {
      if (si <= ti) {
        #pragma unroll
        for (int ks2 = 0; ks2 < 2; ++ks2) {
          bf16x8 bkf = *(const bf16x8*)(kp + ((((size_t)b * 16 + si) * 2 + ks2) * 64 + lane) * 8);
          sacc[si] = __builtin_amdgcn_mfma_f32_16x16x32_bf16(aq[ks2], bkf, sacc[si], 0, 0, 0);
        }
      }
    }

    int trow = t0 + lq * 4;
    #pragma unroll
    for (int si = 0; si < 16; ++si) {
      #pragma unroll
      for (int j = 0; j < 4; ++j) {
        float s = sacc[si][j] * 0.125f;
        if (si * 16 + l15 > trow + j) s = -1e30f;
        sacc[si][j] = s;
      }
    }

    float rl[4];
    #pragma unroll
    for (int j = 0; j < 4; ++j) {
      float mj = -1e30f;
      #pragma unroll
      for (int si = 0; si < 16; ++si) mj = fmaxf(mj, sacc[si][j]);
      #pragma unroll
      for (int d = 1; d < 16; d <<= 1) mj = fmaxf(mj, __shfl_xor(mj, d));
      float lj = 0.0f;
      #pragma unroll
      for (int si = 0; si < 16; ++si) {
        float p = __expf(sacc[si][j] - mj);
        lj += p;
        Pw[(lq * 4 + j) * 264 + si * 16 + l15] = f2bf(p);
      }
      #pragma unroll
      for (int d = 1; d < 16; d <<= 1) lj += __shfl_xor(lj, d);
      rl[j] = 1.0f / lj;
    }

    f32x4 oacc[4];
    #pragma unroll
    for (int nt = 0; nt < 4; ++nt) {
      f32x4 z = {0.f, 0.f, 0.f, 0.f};
      oacc[nt] = z;
    }
    int nk = (t0 + 16 + 31) >> 5;
    for (int ks = 0; ks < nk; ++ks) {
      bf16x8 ap = *(const bf16x8*)&Pw[l15 * 264 + ks * 32 + lq * 8];
      #pragma unroll
      for (int nt = 0; nt < 4; ++nt) {
        bf16x8 bv = *(const bf16x8*)(vp + ((((size_t)b * 4 + nt) * 8 + ks) * 64 + lane) * 8);
        oacc[nt] = __builtin_amdgcn_mfma_f32_16x16x32_bf16(ap, bv, oacc[nt], 0, 0, 0);
      }
    }

    #pragma unroll
    for (int nt = 0; nt < 4; ++nt)
      #pragma unroll
      for (int j = 0; j < 4; ++j)
        ob[(t0 + lq * 4 + j) * H_ + nt * 16 + l15] = oacc[nt][j] * rl[j];
  }
}

extern "C" void kernel_launch(void* const* d_in, const int* in_sizes, int n_in,
                              void* d_out, int out_size, void* d_ws, size_t ws_size,
                              hipStream_t stream) {
  const float* x    = (const float*)d_in[0];
  const float* cosp = (const float*)d_in[1];
  const float* sinp = (const float*)d_in[2];
  const float* Wq   = (const float*)d_in[3];
  const float* Wk   = (const float*)d_in[4];
  const float* Wv   = (const float*)d_in[5];
  float* out = (float*)d_out;

  // ws layout: [0,4096) batch counters | wtp | qp | kp | vp
  const size_t cnt_bytes = 4096;
  const size_t wtp_bytes = 144 * 512 * 2;
  const size_t frag_elems = (size_t)B_ * 16 * 2 * 64 * 8;

  unsigned int* cnt = (unsigned int*)d_ws;
  unsigned short* wtp = (unsigned short*)((char*)d_ws + cnt_bytes);
  unsigned short* qp = (unsigned short*)((char*)d_ws + cnt_bytes + wtp_bytes);
  unsigned short* kp = qp + frag_elems;
  unsigned short* vp = kp + frag_elems;
  (void)ws_size;

  hipMemsetAsync(d_ws, 0, cnt_bytes, stream);   // reset batch counters (replay-safe)
  pack_w_frag<<<288, 256, 0, stream>>>(Wq, Wk, Wv, wtp);
  head_worker<<<4096, 512, 0, stream>>>(x, cosp, sinp, wtp, qp, kp, vp, cnt, out);
}

// Round 12
// 241.509 us; speedup vs baseline: 6.9345x; 6.9345x over previous
//
#include <hip/hip_runtime.h>
#include <hip/hip_bf16.h>

// Round 12: round-10 split structure (205us) + intra-block K-half pipeline in
// qkv: stage half A, issue half B's global loads into registers (held across
// the barrier), run kloop-A with B in flight, then write B and run kloop-B.
// Extends HBM load duty-cycle into the compute phase. attn/pack unchanged.

typedef __attribute__((ext_vector_type(8))) short bf16x8;
typedef __attribute__((ext_vector_type(4))) float f32x4;

#define B_ 1024
#define T_ 256
#define C_ 384
#define H_ 64

static __device__ __forceinline__ unsigned short f2bf(float f) {
  unsigned int u = __float_as_uint(f);
  return (unsigned short)((u + 0x7fffu + ((u >> 16) & 1u)) >> 16);
}

static __device__ __forceinline__ float bf2f(unsigned short h) {
  return __uint_as_float(((unsigned int)h) << 16);
}

static __device__ __forceinline__ bf16x8 cvt8(float4 a, float4 b) {
  union { __hip_bfloat162 h[4]; bf16x8 v; } u;
  u.h[0] = __float22bfloat162_rn(make_float2(a.x, a.y));
  u.h[1] = __float22bfloat162_rn(make_float2(a.z, a.w));
  u.h[2] = __float22bfloat162_rn(make_float2(b.x, b.y));
  u.h[3] = __float22bfloat162_rn(make_float2(b.z, b.w));
  return u.v;
}

// wtp fragment-linear: wtp[((ks*12+nt)*64 + lane)*8 + i] =
//   bf16( W'[n = nt*16 + (lane&15)][k = ks*32 + (lane>>4)*8 + i] )
__global__ void pack_w_frag(const float* __restrict__ Wq, const float* __restrict__ Wk,
                            const float* __restrict__ Wv, unsigned short* __restrict__ wtp) {
  int id = blockIdx.x * 256 + threadIdx.x;
  if (id >= 144 * 512) return;
  int i = id & 7, lane = (id >> 3) & 63, f = id >> 9;
  int nt = f % 12, ks = f / 12;
  int n = nt * 16 + (lane & 15);
  int k = ks * 32 + (lane >> 4) * 8 + i;
  const float* W = (n < 64) ? Wq : ((n < 128) ? Wk : Wv);
  wtp[id] = f2bf(W[k * 64 + (n & 63)]);
}

__launch_bounds__(512, 6)
__global__ void qkv_kernel(const float* __restrict__ x, const float* __restrict__ cosp,
                           const float* __restrict__ sinp,
                           const unsigned short* __restrict__ wtp,
                           unsigned short* __restrict__ qp,
                           unsigned short* __restrict__ kp,
                           unsigned short* __restrict__ vp) {
  // 48 KB: x slab (swizzled bf16); staging tiles alias it post-kloop.
  __shared__ __align__(16) unsigned short xs[64 * 384];

  unsigned short* Qst = xs;                 // [64][72]
  unsigned short* Kst = xs + 64 * 72;
  unsigned short* Vst = xs + 2 * 64 * 72;

  const int tid = threadIdx.x;
  const int w = tid >> 6;
  const int lane = tid & 63;
  const int l15 = lane & 15;
  const int lq = lane >> 4;
  const int bk = blockIdx.x;     // 0..4095
  const int b = bk >> 2, g64 = bk & 3;
  const int row0 = g64 * 64;

  const float* xb = x + (size_t)b * T_ * C_ + (size_t)row0 * C_;

  // Half-chunk helpers: half h covers columns h*24..h*24+23 (K h*192..h*192+191).
  // c in [0,1536): row = c/24, col = c%24 (+24 for half B).
  auto addrH = [&](int c, int h) -> const float* {
    int row = c / 24, col = c - row * 24 + h * 24;
    return xb + (size_t)row * C_ + col * 8;
  };
  auto ldsH = [&](int c, int h) -> char* {
    int row = c / 24, col = c - row * 24 + h * 24;
    return (char*)xs + row * 768 + ((col * 16) ^ ((row & 7) << 4));
  };

  // ---- stage half A (depth-2 over its 3 chunks/thread)
  {
    float4 ca[2], cn[2];
    {
      const float* p = addrH(tid, 0);
      ca[0] = *(const float4*)p; ca[1] = *(const float4*)(p + 4);
    }
    #pragma unroll
    for (int s = 0; s < 3; ++s) {
      if (s + 1 < 3) {
        const float* p = addrH((s + 1) * 512 + tid, 0);
        cn[0] = *(const float4*)p; cn[1] = *(const float4*)(p + 4);
      }
      *(bf16x8*)ldsH(s * 512 + tid, 0) = cvt8(ca[0], ca[1]);
      ca[0] = cn[0]; ca[1] = cn[1];
    }
  }

  // ---- issue ALL half-B global loads now; held in regs across kloop-A
  float4 pb[3][2];
  #pragma unroll
  for (int s = 0; s < 3; ++s) {
    const float* p = addrH(s * 512 + tid, 1);
    pb[s][0] = *(const float4*)p; pb[s][1] = *(const float4*)(p + 4);
  }
  __syncthreads();   // half A visible

  // ---- K-loop setup (acc init after B-issue to shorten live ranges)
  const int ng = w & 3, rset = w >> 2;
  f32x4 acc[2][3];
  #pragma unroll
  for (int i = 0; i < 2; ++i)
    #pragma unroll
    for (int m = 0; m < 3; ++m) {
      f32x4 z = {0.f, 0.f, 0.f, 0.f};
      acc[i][m] = z;
    }

  const int arow0 = (rset * 2) * 16 + l15;
  const int arow1 = (rset * 2 + 1) * 16 + l15;
  const char* xrow0 = (const char*)xs + arow0 * 768;
  const char* xrow1 = (const char*)xs + arow1 * 768;
  const int asw0 = (arow0 & 7) << 4;
  const int asw1 = (arow1 & 7) << 4;

  // ---- kloop half A (ks 0..5); B x-loads remain in flight (wtp loads are
  // younger, so waiting on wtp does not drain them)
  #pragma unroll
  for (int ks = 0; ks < 6; ++ks) {
    bf16x8 bv[3];
    #pragma unroll
    for (int m = 0; m < 3; ++m)
      bv[m] = *(const bf16x8*)(wtp + ((size_t)(ks * 12 + ng * 3 + m) * 64 + lane) * 8);
    bf16x8 a0 = *(const bf16x8*)(xrow0 + ((ks * 64 + lq * 16) ^ asw0));
    bf16x8 a1 = *(const bf16x8*)(xrow1 + ((ks * 64 + lq * 16) ^ asw1));
    #pragma unroll
    for (int m = 0; m < 3; ++m) {
      acc[0][m] = __builtin_amdgcn_mfma_f32_16x16x32_bf16(a0, bv[m], acc[0][m], 0, 0, 0);
      acc[1][m] = __builtin_amdgcn_mfma_f32_16x16x32_bf16(a1, bv[m], acc[1][m], 0, 0, 0);
    }
  }

  // ---- write half B (waits on B loads), then barrier
  #pragma unroll
  for (int s = 0; s < 3; ++s)
    *(bf16x8*)ldsH(s * 512 + tid, 1) = cvt8(pb[s][0], pb[s][1]);
  __syncthreads();   // half B visible

  // ---- kloop half B (ks 6..11)
  #pragma unroll
  for (int ks = 6; ks < 12; ++ks) {
    bf16x8 bv[3];
    #pragma unroll
    for (int m = 0; m < 3; ++m)
      bv[m] = *(const bf16x8*)(wtp + ((size_t)(ks * 12 + ng * 3 + m) * 64 + lane) * 8);
    bf16x8 a0 = *(const bf16x8*)(xrow0 + ((ks * 64 + lq * 16) ^ asw0));
    bf16x8 a1 = *(const bf16x8*)(xrow1 + ((ks * 64 + lq * 16) ^ asw1));
    #pragma unroll
    for (int m = 0; m < 3; ++m) {
      acc[0][m] = __builtin_amdgcn_mfma_f32_16x16x32_bf16(a0, bv[m], acc[0][m], 0, 0, 0);
      acc[1][m] = __builtin_amdgcn_mfma_f32_16x16x32_bf16(a1, bv[m], acc[1][m], 0, 0, 0);
    }
  }
  __syncthreads();   // done reading xs before aliased staging tiles overwrite

  // ---- scatter-stage accumulators (pre-RoPE) into staging tiles (xs region)
  #pragma unroll
  for (int i = 0; i < 2; ++i) {
    #pragma unroll
    for (int m = 0; m < 3; ++m) {
      const int nt = ng * 3 + m;
      #pragma unroll
      for (int j = 0; j < 4; ++j) {
        const int r64 = (rset * 2 + i) * 16 + lq * 4 + j;
        unsigned short v = f2bf(acc[i][m][j]);
        if (nt < 4)      Qst[r64 * 72 + nt * 16 + l15] = v;
        else if (nt < 8) Kst[r64 * 72 + (nt - 4) * 16 + l15] = v;
        else             Vst[((nt - 8) * 16 + l15) * 72 + r64] = v;
      }
    }
  }
  __syncthreads();

  // ---- frag-line writeout: 24 x 1KB lines; RoPE fused on Q/K
  #pragma unroll
  for (int pass = 0; pass < 3; ++pass) {
    const int id = pass * 8 + w;
    if (id < 16) {
      const unsigned short* S = (id < 8) ? Qst : Kst;
      unsigned short* dst = (id < 8) ? qp : kp;
      const int lid = id & 7;
      const int tl = lid >> 1;
      const int ks2 = lid & 1;
      const int r64 = tl * 16 + l15;
      const int c0 = ks2 * 32 + lq * 8;
      const unsigned short* rowp = S + r64 * 72;
      bf16x8 mv = *(const bf16x8*)(rowp + c0);
      bf16x8 pv = *(const bf16x8*)(rowp + (c0 ^ 32));
      const int tglob = row0 + r64;
      const float* cp = cosp + tglob * H_ + c0;
      const float* sp = sinp + tglob * H_ + c0;
      float4 ca = *(const float4*)cp, cb = *(const float4*)(cp + 4);
      float4 sa = *(const float4*)sp, sb = *(const float4*)(sp + 4);
      const float sgn = ks2 ? 1.0f : -1.0f;
      bf16x8 ov;
      ov[0] = (short)f2bf(bf2f((unsigned short)mv[0]) * ca.x + sgn * bf2f((unsigned short)pv[0]) * sa.x);
      ov[1] = (short)f2bf(bf2f((unsigned short)mv[1]) * ca.y + sgn * bf2f((unsigned short)pv[1]) * sa.y);
      ov[2] = (short)f2bf(bf2f((unsigned short)mv[2]) * ca.z + sgn * bf2f((unsigned short)pv[2]) * sa.z);
      ov[3] = (short)f2bf(bf2f((unsigned short)mv[3]) * ca.w + sgn * bf2f((unsigned short)pv[3]) * sa.w);
      ov[4] = (short)f2bf(bf2f((unsigned short)mv[4]) * cb.x + sgn * bf2f((unsigned short)pv[4]) * sb.x);
      ov[5] = (short)f2bf(bf2f((unsigned short)mv[5]) * cb.y + sgn * bf2f((unsigned short)pv[5]) * sb.y);
      ov[6] = (short)f2bf(bf2f((unsigned short)mv[6]) * cb.z + sgn * bf2f((unsigned short)pv[6]) * sb.z);
      ov[7] = (short)f2bf(bf2f((unsigned short)mv[7]) * cb.w + sgn * bf2f((unsigned short)pv[7]) * sb.w);
      const int tile_glob = g64 * 4 + tl;
      *(bf16x8*)(dst + ((((size_t)b * 16 + tile_glob) * 2 + ks2) * 64 + lane) * 8) = ov;
    } else if (id < 24) {
      const int lid = id - 16;
      const int ntv = lid >> 1;
      const int kgl = lid & 1;
      const int ksg = g64 * 2 + kgl;
      bf16x8 fr = *(const bf16x8*)(Vst + (ntv * 16 + l15) * 72 + kgl * 32 + lq * 8);
      *(bf16x8*)(vp + ((((size_t)b * 4 + ntv) * 8 + ksg) * 64 + lane) * 8) = fr;
    }
  }
}

__launch_bounds__(256, 4)
__global__ void attn_kernel(const unsigned short* __restrict__ qp,
                            const unsigned short* __restrict__ kp,
                            const unsigned short* __restrict__ vp,
                            float* __restrict__ out) {
  __shared__ unsigned short Plds[4 * 16 * 264];

  const int tid = threadIdx.x;
  const int w = tid >> 6;
  const int lane = tid & 63;
  const int l15 = lane & 15;
  const int lq = lane >> 4;
  const int bk = blockIdx.x;
  const int b = bk >> 1, half = bk & 1;
  const int rt2[2] = {half * 8 + w, half * 8 + 7 - w};

  unsigned short* Pw = Plds + w * 16 * 264;
  float* ob = out + (size_t)b * T_ * H_;

  #pragma unroll
  for (int i = 0; i < 2; ++i) {
    const int ti = rt2[i];
    const int t0 = ti * 16;

    bf16x8 aq[2];
    #pragma unroll
    for (int ks2 = 0; ks2 < 2; ++ks2)
      aq[ks2] = *(const bf16x8*)(qp + ((((size_t)b * 16 + ti) * 2 + ks2) * 64 + lane) * 8);

    f32x4 sacc[16];
    #pragma unroll
    for (int si = 0; si < 16; ++si) {
      f32x4 z = {0.f, 0.f, 0.f, 0.f};
      sacc[si] = z;
    }

    #pragma unroll
    for (int si = 0; si < 16; ++si) {
      if (si <= ti) {
        #pragma unroll
        for (int ks2 = 0; ks2 < 2; ++ks2) {
          bf16x8 bkf = *(const bf16x8*)(kp + ((((size_t)b * 16 + si) * 2 + ks2) * 64 + lane) * 8);
          sacc[si] = __builtin_amdgcn_mfma_f32_16x16x32_bf16(aq[ks2], bkf, sacc[si], 0, 0, 0);
        }
      }
    }

    int trow = t0 + lq * 4;
    #pragma unroll
    for (int si = 0; si < 16; ++si) {
      #pragma unroll
      for (int j = 0; j < 4; ++j) {
        float s = sacc[si][j] * 0.125f;
        if (si * 16 + l15 > trow + j) s = -1e30f;
        sacc[si][j] = s;
      }
    }

    float rl[4];
    #pragma unroll
    for (int j = 0; j < 4; ++j) {
      float mj = -1e30f;
      #pragma unroll
      for (int si = 0; si < 16; ++si) mj = fmaxf(mj, sacc[si][j]);
      #pragma unroll
      for (int d = 1; d < 16; d <<= 1) mj = fmaxf(mj, __shfl_xor(mj, d));
      float lj = 0.0f;
      #pragma unroll
      for (int si = 0; si < 16; ++si) {
        float p = __expf(sacc[si][j] - mj);
        lj += p;
        Pw[(lq * 4 + j) * 264 + si * 16 + l15] = f2bf(p);
      }
      #pragma unroll
      for (int d = 1; d < 16; d <<= 1) lj += __shfl_xor(lj, d);
      rl[j] = 1.0f / lj;
    }

    f32x4 oacc[4];
    #pragma unroll
    for (int nt = 0; nt < 4; ++nt) {
      f32x4 z = {0.f, 0.f, 0.f, 0.f};
      oacc[nt] = z;
    }
    int nk = (t0 + 16 + 31) >> 5;
    for (int ks = 0; ks < nk; ++ks) {
      bf16x8 ap = *(const bf16x8*)&Pw[l15 * 264 + ks * 32 + lq * 8];
      #pragma unroll
      for (int nt = 0; nt < 4; ++nt) {
        bf16x8 bv = *(const bf16x8*)(vp + ((((size_t)b * 4 + nt) * 8 + ks) * 64 + lane) * 8);
        oacc[nt] = __builtin_amdgcn_mfma_f32_16x16x32_bf16(ap, bv, oacc[nt], 0, 0, 0);
      }
    }

    #pragma unroll
    for (int nt = 0; nt < 4; ++nt)
      #pragma unroll
      for (int j = 0; j < 4; ++j)
        ob[(t0 + lq * 4 + j) * H_ + nt * 16 + l15] = oacc[nt][j] * rl[j];
  }
}

extern "C" void kernel_launch(void* const* d_in, const int* in_sizes, int n_in,
                              void* d_out, int out_size, void* d_ws, size_t ws_size,
                              hipStream_t stream) {
  const float* x    = (const float*)d_in[0];
  const float* cosp = (const float*)d_in[1];
  const float* sinp = (const float*)d_in[2];
  const float* Wq   = (const float*)d_in[3];
  const float* Wk   = (const float*)d_in[4];
  const float* Wv   = (const float*)d_in[5];
  float* out = (float*)d_out;

  const size_t wtp_bytes = 144 * 512 * 2;
  const size_t frag_elems = (size_t)B_ * 16 * 2 * 64 * 8;

  unsigned short* wtp = (unsigned short*)d_ws;
  unsigned short* qp = (unsigned short*)((char*)d_ws + wtp_bytes);
  unsigned short* kp = qp + frag_elems;
  unsigned short* vp = kp + frag_elems;
  (void)ws_size;

  pack_w_frag<<<288, 256, 0, stream>>>(Wq, Wk, Wv, wtp);
  qkv_kernel<<<4096, 512, 0, stream>>>(x, cosp, sinp, wtp, qp, kp, vp);
  attn_kernel<<<B_ * 2, 256, 0, stream>>>(qp, kp, vp, out);
}

// Round 13
// 222.432 us; speedup vs baseline: 7.5292x; 1.0858x over previous
//
#include <hip/hip_runtime.h>
#include <hip/hip_bf16.h>

// Round 13: qkv shrunk to 32-row blocks / 256 threads / 24 KB LDS (staging
// tiles alias the slab) -> 6 blocks/CU, doubling block-level phase overlap.
// attn/pack identical to the 205us round-10 config.

typedef __attribute__((ext_vector_type(8))) short bf16x8;
typedef __attribute__((ext_vector_type(4))) float f32x4;

#define B_ 1024
#define T_ 256
#define C_ 384
#define H_ 64

static __device__ __forceinline__ unsigned short f2bf(float f) {
  unsigned int u = __float_as_uint(f);
  return (unsigned short)((u + 0x7fffu + ((u >> 16) & 1u)) >> 16);
}

static __device__ __forceinline__ float bf2f(unsigned short h) {
  return __uint_as_float(((unsigned int)h) << 16);
}

static __device__ __forceinline__ bf16x8 cvt8(float4 a, float4 b) {
  union { __hip_bfloat162 h[4]; bf16x8 v; } u;
  u.h[0] = __float22bfloat162_rn(make_float2(a.x, a.y));
  u.h[1] = __float22bfloat162_rn(make_float2(a.z, a.w));
  u.h[2] = __float22bfloat162_rn(make_float2(b.x, b.y));
  u.h[3] = __float22bfloat162_rn(make_float2(b.z, b.w));
  return u.v;
}

// wtp fragment-linear: wtp[((ks*12+nt)*64 + lane)*8 + i] =
//   bf16( W'[n = nt*16 + (lane&15)][k = ks*32 + (lane>>4)*8 + i] )
__global__ void pack_w_frag(const float* __restrict__ Wq, const float* __restrict__ Wk,
                            const float* __restrict__ Wv, unsigned short* __restrict__ wtp) {
  int id = blockIdx.x * 256 + threadIdx.x;
  if (id >= 144 * 512) return;
  int i = id & 7, lane = (id >> 3) & 63, f = id >> 9;
  int nt = f % 12, ks = f / 12;
  int n = nt * 16 + (lane & 15);
  int k = ks * 32 + (lane >> 4) * 8 + i;
  const float* W = (n < 64) ? Wq : ((n < 128) ? Wk : Wv);
  wtp[id] = f2bf(W[k * 64 + (n & 63)]);
}

// Q/K packed frag layout: qp[(((b*16+tile)*2+ks2)*64 + L)*8 + i] =
//   Q[b][tile*16 + (L&15)][ks2*32 + (L>>4)*8 + i]   (RoPE applied)
// V packed frag (transposed): vp[(((b*4+nt)*8+ksg)*64 + L)*8 + i] =
//   V[b][ksg*32 + (L>>4)*8 + i][nt*16 + (L&15)]
__launch_bounds__(256, 6)
__global__ void qkv_kernel(const float* __restrict__ x, const float* __restrict__ cosp,
                           const float* __restrict__ sinp,
                           const unsigned short* __restrict__ wtp,
                           unsigned short* __restrict__ qp,
                           unsigned short* __restrict__ kp,
                           unsigned short* __restrict__ vp) {
  // 24 KB: bf16 x slab [32][384] (XOR-swizzled); staging tiles alias it.
  __shared__ __align__(16) unsigned short xs[32 * 384];

  unsigned short* Qst = xs;                  // [32][72] = 2304
  unsigned short* Kst = xs + 2304;           // [32][72]
  unsigned short* Vst = xs + 4608;           // [64][40] = 2560 (total 7168 < 12288)

  const int tid = threadIdx.x;
  const int w = tid >> 6;        // wave 0..3
  const int lane = tid & 63;
  const int l15 = lane & 15;
  const int lq = lane >> 4;
  const int bk = blockIdx.x;     // 0..8191
  const int b = bk >> 3, g32 = bk & 7;
  const int row0 = g32 * 32;

  const float* xb = x + (size_t)b * T_ * C_ + (size_t)row0 * C_;

  // ---- stage x slab: 1536 chunks (8 f32 -> bf16x8), 6/thread, depth-2.
  {
    float4 c0[2], c1[2];
    {
      const float* p = xb + (size_t)tid * 8;
      c0[0] = *(const float4*)p; c0[1] = *(const float4*)(p + 4);
    }
    #pragma unroll
    for (int s = 0; s < 6; ++s) {
      if (s + 1 < 6) {
        const float* p = xb + (size_t)((s + 1) * 256 + tid) * 8;
        c1[0] = *(const float4*)p; c1[1] = *(const float4*)(p + 4);
      }
      int c = s * 256 + tid;
      int row = c / 48;
      int cb = (c - row * 48) * 16;
      *(bf16x8*)((char*)xs + row * 768 + (cb ^ ((row & 7) << 4))) = cvt8(c0[0], c0[1]);
      c0[0] = c1[0]; c0[1] = c1[1];
    }
  }
  __syncthreads();

  // ---- K-loop: wave w owns n-tiles {3w, 3w+1, 3w+2}, both row-tiles.
  const int ng = w;

  f32x4 acc[2][3];
  #pragma unroll
  for (int i = 0; i < 2; ++i)
    #pragma unroll
    for (int m = 0; m < 3; ++m) {
      f32x4 z = {0.f, 0.f, 0.f, 0.f};
      acc[i][m] = z;
    }

  const int arow0 = l15;
  const int arow1 = 16 + l15;
  const char* xrow0 = (const char*)xs + arow0 * 768;
  const char* xrow1 = (const char*)xs + arow1 * 768;
  const int asw0 = (arow0 & 7) << 4;
  const int asw1 = (arow1 & 7) << 4;

  #pragma unroll
  for (int ks = 0; ks < 12; ++ks) {
    bf16x8 bv[3];
    #pragma unroll
    for (int m = 0; m < 3; ++m)
      bv[m] = *(const bf16x8*)(wtp + ((size_t)(ks * 12 + ng * 3 + m) * 64 + lane) * 8);
    bf16x8 a0 = *(const bf16x8*)(xrow0 + ((ks * 64 + lq * 16) ^ asw0));
    bf16x8 a1 = *(const bf16x8*)(xrow1 + ((ks * 64 + lq * 16) ^ asw1));
    #pragma unroll
    for (int m = 0; m < 3; ++m) {
      acc[0][m] = __builtin_amdgcn_mfma_f32_16x16x32_bf16(a0, bv[m], acc[0][m], 0, 0, 0);
      acc[1][m] = __builtin_amdgcn_mfma_f32_16x16x32_bf16(a1, bv[m], acc[1][m], 0, 0, 0);
    }
  }
  __syncthreads();   // done reading xs before aliased staging tiles overwrite

  // ---- scatter-stage accumulators (pre-RoPE)
  #pragma unroll
  for (int i = 0; i < 2; ++i) {
    #pragma unroll
    for (int m = 0; m < 3; ++m) {
      const int nt = ng * 3 + m;
      #pragma unroll
      for (int j = 0; j < 4; ++j) {
        const int r32 = i * 16 + lq * 4 + j;
        unsigned short v = f2bf(acc[i][m][j]);
        if (nt < 4)      Qst[r32 * 72 + nt * 16 + l15] = v;
        else if (nt < 8) Kst[r32 * 72 + (nt - 4) * 16 + l15] = v;
        else             Vst[((nt - 8) * 16 + l15) * 40 + r32] = v;
      }
    }
  }
  __syncthreads();

  // ---- frag-line writeout: 12 x 1KB lines (Q 4, K 4, V 4); RoPE fused on Q/K
  #pragma unroll
  for (int pass = 0; pass < 3; ++pass) {
    const int id = pass * 4 + w;
    if (id < 8) {
      const unsigned short* S = (id < 4) ? Qst : Kst;
      unsigned short* dst = (id < 4) ? qp : kp;
      const int lid = id & 3;
      const int tl = lid >> 1;          // tile within 32-row slab (0..1)
      const int ks2 = lid & 1;
      const int r32 = tl * 16 + l15;
      const int c0 = ks2 * 32 + lq * 8;
      const unsigned short* rowp = S + r32 * 72;
      bf16x8 mv = *(const bf16x8*)(rowp + c0);
      bf16x8 pv = *(const bf16x8*)(rowp + (c0 ^ 32));
      const int tglob = row0 + r32;
      const float* cp = cosp + tglob * H_ + c0;
      const float* sp = sinp + tglob * H_ + c0;
      float4 ca = *(const float4*)cp, cb = *(const float4*)(cp + 4);
      float4 sa = *(const float4*)sp, sb = *(const float4*)(sp + 4);
      const float sgn = ks2 ? 1.0f : -1.0f;
      bf16x8 ov;
      ov[0] = (short)f2bf(bf2f((unsigned short)mv[0]) * ca.x + sgn * bf2f((unsigned short)pv[0]) * sa.x);
      ov[1] = (short)f2bf(bf2f((unsigned short)mv[1]) * ca.y + sgn * bf2f((unsigned short)pv[1]) * sa.y);
      ov[2] = (short)f2bf(bf2f((unsigned short)mv[2]) * ca.z + sgn * bf2f((unsigned short)pv[2]) * sa.z);
      ov[3] = (short)f2bf(bf2f((unsigned short)mv[3]) * ca.w + sgn * bf2f((unsigned short)pv[3]) * sa.w);
      ov[4] = (short)f2bf(bf2f((unsigned short)mv[4]) * cb.x + sgn * bf2f((unsigned short)pv[4]) * sb.x);
      ov[5] = (short)f2bf(bf2f((unsigned short)mv[5]) * cb.y + sgn * bf2f((unsigned short)pv[5]) * sb.y);
      ov[6] = (short)f2bf(bf2f((unsigned short)mv[6]) * cb.z + sgn * bf2f((unsigned short)pv[6]) * sb.z);
      ov[7] = (short)f2bf(bf2f((unsigned short)mv[7]) * cb.w + sgn * bf2f((unsigned short)pv[7]) * sb.w);
      const int tile_glob = g32 * 2 + tl;
      *(bf16x8*)(dst + ((((size_t)b * 16 + tile_glob) * 2 + ks2) * 64 + lane) * 8) = ov;
    } else if (id < 12) {
      const int ntv = id - 8;
      bf16x8 fr = *(const bf16x8*)(Vst + (ntv * 16 + l15) * 40 + lq * 8);
      *(bf16x8*)(vp + ((((size_t)b * 4 + ntv) * 8 + g32) * 64 + lane) * 8) = fr;
    }
  }
}

__launch_bounds__(256, 4)
__global__ void attn_kernel(const unsigned short* __restrict__ qp,
                            const unsigned short* __restrict__ kp,
                            const unsigned short* __restrict__ vp,
                            float* __restrict__ out) {
  __shared__ unsigned short Plds[4 * 16 * 264];

  const int tid = threadIdx.x;
  const int w = tid >> 6;
  const int lane = tid & 63;
  const int l15 = lane & 15;
  const int lq = lane >> 4;
  const int bk = blockIdx.x;
  const int b = bk >> 1, half = bk & 1;
  const int rt2[2] = {half * 8 + w, half * 8 + 7 - w};

  unsigned short* Pw = Plds + w * 16 * 264;
  float* ob = out + (size_t)b * T_ * H_;

  #pragma unroll
  for (int i = 0; i < 2; ++i) {
    const int ti = rt2[i];
    const int t0 = ti * 16;

    bf16x8 aq[2];
    #pragma unroll
    for (int ks2 = 0; ks2 < 2; ++ks2)
      aq[ks2] = *(const bf16x8*)(qp + ((((size_t)b * 16 + ti) * 2 + ks2) * 64 + lane) * 8);

    f32x4 sacc[16];
    #pragma unroll
    for (int si = 0; si < 16; ++si) {
      f32x4 z = {0.f, 0.f, 0.f, 0.f};
      sacc[si] = z;
    }

    #pragma unroll
    for (int si = 0; si < 16; ++si) {
      if (si <= ti) {  // wave-uniform causal tile skip
        #pragma unroll
        for (int ks2 = 0; ks2 < 2; ++ks2) {
          bf16x8 bkf = *(const bf16x8*)(kp + ((((size_t)b * 16 + si) * 2 + ks2) * 64 + lane) * 8);
          sacc[si] = __builtin_amdgcn_mfma_f32_16x16x32_bf16(aq[ks2], bkf, sacc[si], 0, 0, 0);
        }
      }
    }

    int trow = t0 + lq * 4;
    #pragma unroll
    for (int si = 0; si < 16; ++si) {
      #pragma unroll
      for (int j = 0; j < 4; ++j) {
        float s = sacc[si][j] * 0.125f;
        if (si * 16 + l15 > trow + j) s = -1e30f;
        sacc[si][j] = s;
      }
    }

    float rl[4];
    #pragma unroll
    for (int j = 0; j < 4; ++j) {
      float mj = -1e30f;
      #pragma unroll
      for (int si = 0; si < 16; ++si) mj = fmaxf(mj, sacc[si][j]);
      #pragma unroll
      for (int d = 1; d < 16; d <<= 1) mj = fmaxf(mj, __shfl_xor(mj, d));
      float lj = 0.0f;
      #pragma unroll
      for (int si = 0; si < 16; ++si) {
        float p = __expf(sacc[si][j] - mj);
        lj += p;
        Pw[(lq * 4 + j) * 264 + si * 16 + l15] = f2bf(p);
      }
      #pragma unroll
      for (int d = 1; d < 16; d <<= 1) lj += __shfl_xor(lj, d);
      rl[j] = 1.0f / lj;
    }

    f32x4 oacc[4];
    #pragma unroll
    for (int nt = 0; nt < 4; ++nt) {
      f32x4 z = {0.f, 0.f, 0.f, 0.f};
      oacc[nt] = z;
    }
    int nk = (t0 + 16 + 31) >> 5;
    for (int ks = 0; ks < nk; ++ks) {
      bf16x8 ap = *(const bf16x8*)&Pw[l15 * 264 + ks * 32 + lq * 8];
      #pragma unroll
      for (int nt = 0; nt < 4; ++nt) {
        bf16x8 bv = *(const bf16x8*)(vp + ((((size_t)b * 4 + nt) * 8 + ks) * 64 + lane) * 8);
        oacc[nt] = __builtin_amdgcn_mfma_f32_16x16x32_bf16(ap, bv, oacc[nt], 0, 0, 0);
      }
    }

    #pragma unroll
    for (int nt = 0; nt < 4; ++nt)
      #pragma unroll
      for (int j = 0; j < 4; ++j)
        ob[(t0 + lq * 4 + j) * H_ + nt * 16 + l15] = oacc[nt][j] * rl[j];
  }
}

extern "C" void kernel_launch(void* const* d_in, const int* in_sizes, int n_in,
                              void* d_out, int out_size, void* d_ws, size_t ws_size,
                              hipStream_t stream) {
  const float* x    = (const float*)d_in[0];
  const float* cosp = (const float*)d_in[1];
  const float* sinp = (const float*)d_in[2];
  const float* Wq   = (const float*)d_in[3];
  const float* Wk   = (const float*)d_in[4];
  const float* Wv   = (const float*)d_in[5];
  float* out = (float*)d_out;

  const size_t wtp_bytes = 144 * 512 * 2;
  const size_t frag_elems = (size_t)B_ * 16 * 2 * 64 * 8;

  unsigned short* wtp = (unsigned short*)d_ws;
  unsigned short* qp = (unsigned short*)((char*)d_ws + wtp_bytes);
  unsigned short* kp = qp + frag_elems;
  unsigned short* vp = kp + frag_elems;
  (void)ws_size;

  pack_w_frag<<<288, 256, 0, stream>>>(Wq, Wk, Wv, wtp);
  qkv_kernel<<<B_ * 8, 256, 0, stream>>>(x, cosp, sinp, wtp, qp, kp, vp);
  attn_kernel<<<B_ * 2, 256, 0, stream>>>(qp, kp, vp, out);
}